// Round 4
// baseline (6171.774 us; speedup 1.0000x reference)
//
#include <hip/hip_runtime.h>
#include <cmath>

#define T_FULL 512
#define DMODEL 1024
#define NHEADS 16
#define HDIM 64
#define HD2 32
#define DFF 2816
#define EPS_DEF 1.1920928955078125e-07f
#define EPS_HEAD 1e-05f
#define SCALING 0.17677669529663687f   /* 1/sqrt(32) */

// ---------------------------------------------------------------------------
// Embed: h[b,0,:] = sep_emb[sep[b]]/32 ; h[b,t,:] = (x[b,t-1,:]@Wi^T + bi)/32
// ---------------------------------------------------------------------------
__global__ __launch_bounds__(256) void embed_kernel(
    const float* __restrict__ x, const int* __restrict__ sep,
    const float* __restrict__ sep_emb, const float* __restrict__ Wi,
    const float* __restrict__ bi, float* __restrict__ h)
{
    const int row = blockIdx.x;            // b*512 + t
    const int t = row & 511, b = row >> 9;
    const int tid = threadIdx.x;
    const float inv = 1.0f / 32.0f;
    if (t == 0) {
        const int idx = sep[b];
        for (int d = tid; d < DMODEL; d += 256)
            h[(size_t)row * DMODEL + d] = sep_emb[(size_t)idx * DMODEL + d] * inv;
        return;
    }
    __shared__ float xs[64];
    if (tid < 64) xs[tid] = x[((size_t)(b * 511 + (t - 1))) * 64 + tid];
    __syncthreads();
    for (int d = tid; d < DMODEL; d += 256) {
        float acc = bi[d];
        const float* wr = Wi + (size_t)d * 64;
        #pragma unroll 16
        for (int f = 0; f < 64; ++f) acc += xs[f] * wr[f];
        h[(size_t)row * DMODEL + d] = acc * inv;
    }
}

// ---------------------------------------------------------------------------
// Row RMS-norm over 1024: y = x * rsqrt(mean(x^2)+eps) * w
// ---------------------------------------------------------------------------
__global__ __launch_bounds__(256) void rms_kernel(
    const float* __restrict__ x, const float* __restrict__ w,
    float* __restrict__ y, float eps)
{
    const int row = blockIdx.x;
    const int tid = threadIdx.x;
    const float4 xv = reinterpret_cast<const float4*>(x + (size_t)row * DMODEL)[tid];
    float ss = xv.x * xv.x + xv.y * xv.y + xv.z * xv.z + xv.w * xv.w;
    #pragma unroll
    for (int off = 1; off < 64; off <<= 1) ss += __shfl_xor(ss, off);
    __shared__ float tmp[4];
    if ((tid & 63) == 0) tmp[tid >> 6] = ss;
    __syncthreads();
    ss = tmp[0] + tmp[1] + tmp[2] + tmp[3];
    const float scale = rsqrtf(ss * (1.0f / 1024.0f) + eps);
    const float4 wv = reinterpret_cast<const float4*>(w)[tid];
    float4 o;
    o.x = xv.x * scale * wv.x;
    o.y = xv.y * scale * wv.y;
    o.z = xv.z * scale * wv.z;
    o.w = xv.w * scale * wv.w;
    reinterpret_cast<float4*>(y + (size_t)row * DMODEL)[tid] = o;
}

// ---------------------------------------------------------------------------
// GEMM: C[M,N] (+)= A[M,K(lda)] @ W[N,K]^T + bias[N]
// tile 64x32, 256 threads, each thread 4x2
// ---------------------------------------------------------------------------
template <bool ACCUM>
__global__ __launch_bounds__(256) void gemm_bt_kernel(
    const float* __restrict__ A, const float* __restrict__ W,
    const float* __restrict__ bias, float* __restrict__ C,
    int M, int N, int K, int lda)
{
    __shared__ __align__(16) float As[16][64];
    __shared__ __align__(16) float Ws[16][32];
    const int tid = threadIdx.x;
    const int bn = blockIdx.x, bm = blockIdx.y;
    const int tx = tid & 15, ty = tid >> 4;

    const int alr = tid >> 2;            // 0..63
    const int alc = (tid & 3) << 2;      // 0,4,8,12
    const int wlr = tid >> 3;            // 0..31
    const int wlc = (tid & 7) << 1;      // 0,2,...,14

    const float* Ap = A + (size_t)(bm * 64 + alr) * lda + alc;
    const float* Wp = W + (size_t)(bn * 32 + wlr) * K + wlc;

    float acc[4][2] = {};
    for (int k0 = 0; k0 < K; k0 += 16) {
        const float4 a4 = *reinterpret_cast<const float4*>(Ap + k0);
        const float2 w2 = *reinterpret_cast<const float2*>(Wp + k0);
        __syncthreads();
        As[alc + 0][alr] = a4.x;
        As[alc + 1][alr] = a4.y;
        As[alc + 2][alr] = a4.z;
        As[alc + 3][alr] = a4.w;
        Ws[wlc + 0][wlr] = w2.x;
        Ws[wlc + 1][wlr] = w2.y;
        __syncthreads();
        #pragma unroll
        for (int kk = 0; kk < 16; ++kk) {
            const float4 av = *reinterpret_cast<const float4*>(&As[kk][ty << 2]);
            const float2 wv = *reinterpret_cast<const float2*>(&Ws[kk][tx << 1]);
            acc[0][0] += av.x * wv.x; acc[0][1] += av.x * wv.y;
            acc[1][0] += av.y * wv.x; acc[1][1] += av.y * wv.y;
            acc[2][0] += av.z * wv.x; acc[2][1] += av.z * wv.y;
            acc[3][0] += av.w * wv.x; acc[3][1] += av.w * wv.y;
        }
    }
    const int row = bm * 64 + (ty << 2);
    const int col = bn * 32 + (tx << 1);
    #pragma unroll
    for (int i = 0; i < 4; ++i) {
        #pragma unroll
        for (int j = 0; j < 2; ++j) {
            float r = acc[i][j] + bias[col + j];
            if (ACCUM) r += C[(size_t)(row + i) * N + col + j];
            C[(size_t)(row + i) * N + col + j] = r;
        }
    }
}

// ---------------------------------------------------------------------------
// RoPE in place on q and k: tokens t>=1 use cos/sin row (t-1); 16 pairs/head
// ---------------------------------------------------------------------------
__global__ __launch_bounds__(256) void rope_kernel(
    float* __restrict__ q, float* __restrict__ k,
    const float* __restrict__ cs, const float* __restrict__ sn)
{
    const int i = blockIdx.x * 256 + threadIdx.x;   // over B*511*32*16
    if (i >= 2 * 511 * 32 * 16) return;
    const int pr = i & 15;
    const int r1 = i >> 4;
    const int hh = r1 & 31;
    const int r2 = r1 >> 5;
    const int t1 = r2 % 511;
    const int b  = r2 / 511;
    const float c = cs[t1 * 16 + pr];
    const float s = sn[t1 * 16 + pr];
    const size_t base = ((size_t)((b * 512 + (t1 + 1)) * 32 + hh)) * 32 + 2 * pr;
    {
        const float xr = q[base], xi = q[base + 1];
        q[base]     = xr * c - xi * s;
        q[base + 1] = xr * s + xi * c;
    }
    {
        const float xr = k[base], xi = k[base + 1];
        k[base]     = xr * c - xi * s;
        k[base + 1] = xr * s + xi * c;
    }
}

// ---------------------------------------------------------------------------
// Fused DINT attention, one block per (b, head n, query row tq). 128 threads.
// ---------------------------------------------------------------------------
__device__ __forceinline__ float bred_max(float v) {
    #pragma unroll
    for (int off = 1; off < 64; off <<= 1) v = fmaxf(v, __shfl_xor(v, off));
    __shared__ float t[2];
    if ((threadIdx.x & 63) == 0) t[threadIdx.x >> 6] = v;
    __syncthreads();
    v = fmaxf(t[0], t[1]);
    __syncthreads();
    return v;
}
__device__ __forceinline__ float bred_sum(float v) {
    #pragma unroll
    for (int off = 1; off < 64; off <<= 1) v += __shfl_xor(v, off);
    __shared__ float t[2];
    if ((threadIdx.x & 63) == 0) t[threadIdx.x >> 6] = v;
    __syncthreads();
    v = t[0] + t[1];
    __syncthreads();
    return v;
}

__global__ __launch_bounds__(128) void attn_kernel(
    const float* __restrict__ q, const float* __restrict__ k,
    const float* __restrict__ v,
    const float* __restrict__ lq1, const float* __restrict__ lq2,
    const float* __restrict__ lk1, const float* __restrict__ lk2,
    float lam_init, float* __restrict__ o)
{
    const int idx = blockIdx.x;
    const int tq = idx & 511;
    const int n  = (idx >> 9) & 15;
    const int b  = idx >> 13;
    const int tid = threadIdx.x;

    __shared__ float p0[T_FULL], p1[T_FULL];
    __shared__ float qs[64];
    __shared__ float lam_s;
    __shared__ float redpv[128];

    const float* qb = q + ((size_t)((b * 512 + tq) * 32 + 2 * n)) * 32;
    if (tid < 64) qs[tid] = qb[tid];
    if (tid == 0) {
        float s1 = 0.f, s2 = 0.f;
        #pragma unroll
        for (int i = 0; i < 32; ++i) { s1 += lk1[i] * lq1[i]; s2 += lk2[i] * lq2[i]; }
        lam_s = expf(s1) - expf(s2) + lam_init;
    }
    __syncthreads();
    const float lam = lam_s;

    float m0 = -1e30f, m1 = -1e30f;
    for (int t = tid; t <= tq; t += 128) {
        const float* kb = k + ((size_t)((b * 512 + t) * 32 + 2 * n)) * 32;
        float d0 = 0.f, d1 = 0.f;
        #pragma unroll
        for (int j = 0; j < 32; ++j) { d0 += qs[j] * kb[j]; d1 += qs[32 + j] * kb[32 + j]; }
        d0 *= SCALING; d1 *= SCALING;
        p0[t] = d0; p1[t] = d1;
        m0 = fmaxf(m0, d0); m1 = fmaxf(m1, d1);
    }
    m0 = bred_max(m0);
    m1 = bred_max(m1);

    float s0 = 0.f, s1 = 0.f;
    for (int t = tid; t <= tq; t += 128) {
        const float e0 = expf(p0[t] - m0);
        const float e1 = expf(p1[t] - m1);
        p0[t] = e0; p1[t] = e1;
        s0 += e0; s1 += e1;
    }
    s0 = bred_sum(s0);
    s1 = bred_sum(s1);
    const float inv0 = 1.0f / s0, inv1 = 1.0f / s1;

    float sn = 0.f;
    for (int t = tid; t <= tq; t += 128) {
        const float a0 = p0[t] * inv0;
        const float a1 = p1[t] * inv1;
        sn += a1;
        p0[t] = a0 - lam * a1;
    }
    sn = bred_sum(sn);
    const float a3 = lam * sn / (float)(tq + 1);
    for (int t = tid; t <= tq; t += 128) p0[t] += a3;
    __syncthreads();

    const int d  = tid & 63;
    const int ko = tid >> 6;
    float acc = 0.f;
    for (int t = ko; t <= tq; t += 2)
        acc += p0[t] * v[((size_t)((b * 512 + t) * 16 + n)) * 64 + d];
    redpv[tid] = acc;
    __syncthreads();
    if (tid < 64)
        o[((size_t)((b * 512 + tq) * 16 + n)) * 64 + d] = redpv[tid] + redpv[tid + 64];
}

// ---------------------------------------------------------------------------
// Per-head RMS over HD=64 with weight hw, then SCRAMBLED store matching the
// reference's  (B,H,T,HD).reshape(B,T,D):
//   value(b, head n, token t, dim d)  →  y[b, n*32 + t/16, (t%16)*64 + d]
// ---------------------------------------------------------------------------
__global__ __launch_bounds__(64) void headrms_kernel(
    const float* __restrict__ o, const float* __restrict__ hw,
    float* __restrict__ y)
{
    const int idx = blockIdx.x;          // (b*512+t)*16+n
    const int d = threadIdx.x;
    const int n = idx & 15;
    const int bt = idx >> 4;
    const int t = bt & 511;
    const int b = bt >> 9;
    const float xv = o[(size_t)idx * 64 + d];
    float ss = xv * xv;
    #pragma unroll
    for (int off = 1; off < 64; off <<= 1) ss += __shfl_xor(ss, off);
    const float scale = rsqrtf(ss * (1.0f / 64.0f) + EPS_HEAD);
    const int row_out = b * 512 + n * 32 + (t >> 4);
    const int col_out = (t & 15) * 64 + d;
    y[(size_t)row_out * DMODEL + col_out] = xv * scale * hw[d];
}

// ---------------------------------------------------------------------------
// SwiGLU in place: uv[m, e] = u * silu(g),  u=uv[m,e], g=uv[m,2816+e]
// ---------------------------------------------------------------------------
__global__ __launch_bounds__(256) void swiglu_kernel(float* __restrict__ uv)
{
    const int i = blockIdx.x * 256 + threadIdx.x;
    if (i >= 1024 * DFF) return;
    const int m = i / DFF, e = i - m * DFF;
    const float u = uv[(size_t)m * (2 * DFF) + e];
    const float g = uv[(size_t)m * (2 * DFF) + DFF + e];
    uv[(size_t)m * (2 * DFF) + e] = u * g / (1.0f + expf(-g));
}

// ---------------------------------------------------------------------------
// Final: out[row, p] = rms(h,nfw) @ Wp^T + bp   (p = 0..3)
// ---------------------------------------------------------------------------
__global__ __launch_bounds__(256) void final_kernel(
    const float* __restrict__ h, const float* __restrict__ nfw,
    const float* __restrict__ Wp, const float* __restrict__ bp,
    float* __restrict__ out, float eps)
{
    const int row = blockIdx.x;
    const int tid = threadIdx.x;
    const float4 xv = reinterpret_cast<const float4*>(h + (size_t)row * DMODEL)[tid];
    float ss = xv.x * xv.x + xv.y * xv.y + xv.z * xv.z + xv.w * xv.w;
    #pragma unroll
    for (int off = 1; off < 64; off <<= 1) ss += __shfl_xor(ss, off);
    __shared__ float tmp[4];
    if ((tid & 63) == 0) tmp[tid >> 6] = ss;
    __syncthreads();
    ss = tmp[0] + tmp[1] + tmp[2] + tmp[3];
    const float scale = rsqrtf(ss * (1.0f / 1024.0f) + eps);
    const float4 wv = reinterpret_cast<const float4*>(nfw)[tid];
    float nx[4] = { xv.x * scale * wv.x, xv.y * scale * wv.y,
                    xv.z * scale * wv.z, xv.w * scale * wv.w };
    float p[4];
    #pragma unroll
    for (int j = 0; j < 4; ++j) {
        const float* wr = Wp + (size_t)j * DMODEL + (tid << 2);
        p[j] = nx[0] * wr[0] + nx[1] * wr[1] + nx[2] * wr[2] + nx[3] * wr[3];
    }
    #pragma unroll
    for (int j = 0; j < 4; ++j) {
        #pragma unroll
        for (int off = 1; off < 64; off <<= 1) p[j] += __shfl_xor(p[j], off);
    }
    __shared__ float t4[4][4];
    if ((tid & 63) == 0) {
        #pragma unroll
        for (int j = 0; j < 4; ++j) t4[tid >> 6][j] = p[j];
    }
    __syncthreads();
    if (tid < 4)
        out[(size_t)row * 4 + tid] =
            t4[0][tid] + t4[1][tid] + t4[2][tid] + t4[3][tid] + bp[tid];
}

// ---------------------------------------------------------------------------
extern "C" void kernel_launch(void* const* d_in, const int* in_sizes, int n_in,
                              void* d_out, int out_size, void* d_ws, size_t ws_size,
                              hipStream_t stream)
{
    (void)in_sizes; (void)n_in; (void)out_size; (void)ws_size;

    const float* x       = (const float*)d_in[0];
    const int*   sep     = (const int*)  d_in[1];
    const float* Wq      = (const float*)d_in[2];
    const float* bq      = (const float*)d_in[3];
    const float* Wk      = (const float*)d_in[4];
    const float* bk      = (const float*)d_in[5];
    const float* Wv      = (const float*)d_in[6];
    const float* bv      = (const float*)d_in[7];
    const float* Wo      = (const float*)d_in[8];
    const float* bo      = (const float*)d_in[9];
    const float* lq1     = (const float*)d_in[10];
    const float* lq2     = (const float*)d_in[11];
    const float* lk1     = (const float*)d_in[12];
    const float* lk2     = (const float*)d_in[13];
    const float* hw      = (const float*)d_in[14];
    const float* n1w     = (const float*)d_in[15];
    const float* n2w     = (const float*)d_in[16];
    const float* Wg      = (const float*)d_in[17];
    const float* bg      = (const float*)d_in[18];
    const float* Wf      = (const float*)d_in[19];
    const float* bf      = (const float*)d_in[20];
    const float* Wi      = (const float*)d_in[21];
    const float* bi      = (const float*)d_in[22];
    const float* nfw     = (const float*)d_in[23];
    const float* Wp      = (const float*)d_in[24];
    const float* bp      = (const float*)d_in[25];
    const float* sep_emb = (const float*)d_in[26];
    const float* cosb    = (const float*)d_in[27];
    const float* sinb    = (const float*)d_in[28];
    float* out = (float*)d_out;

    const int M = 2 * T_FULL;                 // 1024 rows
    const size_t MD = (size_t)M * DMODEL;     // 1048576

    float* ws   = (float*)d_ws;
    float* h    = ws;                         // 1M floats
    float* xn   = h + MD;                     // 1M floats (also y)
    float* pool = xn + MD;                    // max(q+k+v+o, uv) = 5.767M floats
    float* qb   = pool;
    float* kb   = pool + MD;
    float* vb   = pool + 2 * MD;
    float* ob   = pool + 3 * MD;
    float* uv   = pool;                       // overlays q/k/v/o (dead by FFN)

    embed_kernel<<<M, 256, 0, stream>>>(x, sep, sep_emb, Wi, bi, h);

    for (int l = 0; l < 6; ++l) {
        const float* Wq_l = Wq + (size_t)l * DMODEL * DMODEL;
        const float* Wk_l = Wk + (size_t)l * DMODEL * DMODEL;
        const float* Wv_l = Wv + (size_t)l * DMODEL * DMODEL;
        const float* Wo_l = Wo + (size_t)l * DMODEL * DMODEL;
        const float* bq_l = bq + (size_t)l * DMODEL;
        const float* bk_l = bk + (size_t)l * DMODEL;
        const float* bv_l = bv + (size_t)l * DMODEL;
        const float* bo_l = bo + (size_t)l * DMODEL;
        const float* Wg_l = Wg + (size_t)l * (2 * DFF) * DMODEL;
        const float* bg_l = bg + (size_t)l * (2 * DFF);
        const float* Wf_l = Wf + (size_t)l * DMODEL * DFF;
        const float* bf_l = bf + (size_t)l * DMODEL;
        const float* lq1_l = lq1 + l * HD2, *lq2_l = lq2 + l * HD2;
        const float* lk1_l = lk1 + l * HD2, *lk2_l = lk2 + l * HD2;
        const float* hw_l  = hw + l * HDIM;
        const float* n1w_l = n1w + (size_t)l * DMODEL;
        const float* n2w_l = n2w + (size_t)l * DMODEL;
        const float lam_init = (float)(0.8 - 0.6 * exp(-0.3 * (double)l));

        // ---- attention block ----
        rms_kernel<<<M, 256, 0, stream>>>(h, n1w_l, xn, EPS_DEF);
        gemm_bt_kernel<false><<<dim3(DMODEL / 32, M / 64), 256, 0, stream>>>(
            xn, Wq_l, bq_l, qb, M, DMODEL, DMODEL, DMODEL);
        gemm_bt_kernel<false><<<dim3(DMODEL / 32, M / 64), 256, 0, stream>>>(
            xn, Wk_l, bk_l, kb, M, DMODEL, DMODEL, DMODEL);
        gemm_bt_kernel<false><<<dim3(DMODEL / 32, M / 64), 256, 0, stream>>>(
            xn, Wv_l, bv_l, vb, M, DMODEL, DMODEL, DMODEL);
        rope_kernel<<<(2 * 511 * 32 * 16 + 255) / 256, 256, 0, stream>>>(
            qb, kb, cosb, sinb);
        attn_kernel<<<2 * NHEADS * T_FULL, 128, 0, stream>>>(
            qb, kb, vb, lq1_l, lq2_l, lk1_l, lk2_l, lam_init, ob);
        headrms_kernel<<<M * NHEADS, 64, 0, stream>>>(ob, hw_l, xn);
        gemm_bt_kernel<true><<<dim3(DMODEL / 32, M / 64), 256, 0, stream>>>(
            xn, Wo_l, bo_l, h, M, DMODEL, DMODEL, DMODEL);

        // ---- FFN block ----
        rms_kernel<<<M, 256, 0, stream>>>(h, n2w_l, xn, EPS_DEF);
        gemm_bt_kernel<false><<<dim3((2 * DFF) / 32, M / 64), 256, 0, stream>>>(
            xn, Wg_l, bg_l, uv, M, 2 * DFF, DMODEL, DMODEL);
        swiglu_kernel<<<(M * DFF + 255) / 256, 256, 0, stream>>>(uv);
        gemm_bt_kernel<true><<<dim3(DMODEL / 32, M / 64), 256, 0, stream>>>(
            uv, Wf_l, bf_l, h, M, DMODEL, DFF, 2 * DFF);
    }

    final_kernel<<<M, 256, 0, stream>>>(h, nfw, Wp, bp, out, EPS_DEF);
}